// Round 1
// baseline (1627.851 us; speedup 1.0000x reference)
//
#include <hip/hip_runtime.h>
#include <hip/hip_bf16.h>

#define HIDDEN 256
#define H2 128
#define NCOLS 384          // 128 gate-hidden cols + 256 value cols
#define NUM_GRAPHS 8192
#define GPB 2              // graphs per block (sorted batch => contiguous rows)

typedef short bf16x8 __attribute__((ext_vector_type(8)));
typedef float f32x4 __attribute__((ext_vector_type(4)));

__device__ __forceinline__ unsigned short f32_bf16_rne(float f) {
  union { float f; unsigned int u; } v; v.f = f;
  unsigned int u = v.u;
  unsigned int lsb = (u >> 16) & 1u;
  u += 0x7fffu + lsb;
  return (unsigned short)(u >> 16);
}

__device__ __forceinline__ float silu_f(float h) {
  return h / (1.0f + __expf(-h));
}

// seg[g] = first node index whose batch >= g ; seg[NUM_GRAPHS] = N
__global__ void seg_starts_kernel(const int* __restrict__ batch,
                                  int* __restrict__ seg, int N) {
  int i = blockIdx.x * blockDim.x + threadIdx.x;
  if (i >= N) return;
  int cur = batch[i];
  int prev = (i == 0) ? -1 : batch[i - 1];
  for (int g = prev + 1; g <= cur; ++g) seg[g] = i;
  if (i == N - 1)
    for (int g = cur + 1; g <= NUM_GRAPHS; ++g) seg[g] = N;
}

// Wt2[(k>>3)*NCOLS*8 + n*8 + (k&7)] = bf16(W[k][n]); W = [w_g1 | w_v]
// Layout makes a wave's MFMA B-fragment load fully coalesced from global/L2.
__global__ void convert_w_kernel(const float* __restrict__ w_g1,
                                 const float* __restrict__ w_v,
                                 unsigned short* __restrict__ Wt2) {
  int idx = blockIdx.x * blockDim.x + threadIdx.x;   // 0 .. 98303
  int j  = idx & 7;
  int n  = (idx >> 3) % NCOLS;
  int kc = idx / (NCOLS * 8);
  int k  = kc * 8 + j;
  float v = (n < H2) ? w_g1[k * H2 + n] : w_v[k * HIDDEN + (n - H2)];
  Wt2[idx] = f32_bf16_rne(v);
}

// Value GEMM in 2 tn-chunks of 32 acc regs each, fold immediately -> peak
// unified regs ~100 (was ~130 with accv[4][4]=64 acc, which spilled ~1 GB of
// scratch traffic per dispatch at the 128-reg cap of __launch_bounds__(256,4)).
// CH, tn compile-time so vacc indexing stays static (no scratch).
#define VALUE_CHUNK(CH)                                                       \
  {                                                                           \
    f32x4 accv[4][2];                                                         \
    _Pragma("unroll")                                                         \
    for (int mt = 0; mt < 4; ++mt)                                            \
      _Pragma("unroll")                                                       \
      for (int tn = 0; tn < 2; ++tn)                                          \
        accv[mt][tn] = (f32x4){0.f, 0.f, 0.f, 0.f};                           \
    _Pragma("unroll")                                                         \
    for (int c = 0; c < 8; ++c) {                                             \
      bf16x8 a[4];                                                            \
      _Pragma("unroll")                                                       \
      for (int mt = 0; mt < 4; ++mt)                                          \
        a[mt] = *(const bf16x8*)&As[(mt * 16 + l15) * 264 + c * 32 + quad * 8]; \
      int kc = c * 4 + quad;                                                  \
      _Pragma("unroll")                                                       \
      for (int tn = 0; tn < 2; ++tn) {                                        \
        int n = (w + 4 * ((CH) * 2 + tn + 2)) * 16 + l15;                     \
        bf16x8 b = *(const bf16x8*)(Wt2 + (((kc * NCOLS) + n) << 3));         \
        _Pragma("unroll")                                                     \
        for (int mt = 0; mt < 4; ++mt)                                        \
          accv[mt][tn] = __builtin_amdgcn_mfma_f32_16x16x32_bf16(             \
              a[mt], b, accv[mt][tn], 0, 0, 0);                               \
      }                                                                       \
    }                                                                         \
    _Pragma("unroll")                                                         \
    for (int mt = 0; mt < 4; ++mt)                                            \
      _Pragma("unroll")                                                       \
      for (int r = 0; r < 4; ++r) {                                           \
        int row  = mt * 16 + quad * 4 + r;                                    \
        int node = node0 + row;                                               \
        float e  = es[row];                                                   \
        float se0 = (node < split) ? e : 0.f;                                 \
        float se1 = e - se0;                                                  \
        _Pragma("unroll")                                                     \
        for (int tn = 0; tn < 2; ++tn) {                                      \
          float s = silu_f(accv[mt][tn][r] + bvr[(CH) * 2 + tn]);             \
          vacc0[(CH) * 2 + tn] += se0 * s;                                    \
          vacc1[(CH) * 2 + tn] += se1 * s;                                    \
        }                                                                     \
      }                                                                       \
  }

// 4 blocks/CU: LDS 35 KB * 4 = 140 <= 160 KB; unified VGPR cap 128.
// Peak live with chunked value GEMM ~100 regs -> no scratch spill.
__launch_bounds__(256, 4)
__global__ void attn_readout_kernel(
    const float* __restrict__ x,
    const float* __restrict__ b_g1,
    const float* __restrict__ w_g2,
    const float* __restrict__ b_g2,
    const float* __restrict__ b_v,
    const unsigned short* __restrict__ Wt2,
    const int* __restrict__ seg,
    float* __restrict__ out)
{
  // row stride 264 shorts (+8 pad)
  __shared__ unsigned short As[64 * 264];
  __shared__ float gate_part[4][64];
  __shared__ float es[64];
  __shared__ float denom_s[2];

  const int tid  = threadIdx.x;
  const int w    = tid >> 6;        // wave 0..3
  const int lane = tid & 63;
  const int l15  = lane & 15;
  const int quad = lane >> 4;

  const int g0      = blockIdx.x * GPB;
  const int node_lo = seg[g0];
  const int split   = seg[g0 + 1];   // first node of graph g0+1
  const int node_hi = seg[g0 + 2];

  // per-lane constants: wave w owns n-tiles {w, w+4, ..., w+20}
  float bg1r[2], wg2r[2], bvr[4];
#pragma unroll
  for (int i = 0; i < 2; ++i) {
    int col = (w + 4 * i) * 16 + l15;               // gate cols [0,128)
    bg1r[i] = b_g1[col];
    wg2r[i] = w_g2[col];
  }
#pragma unroll
  for (int i = 0; i < 4; ++i) {
    int colv = (w + 4 * (i + 2)) * 16 + l15 - 128;  // value cols [0,256)
    bvr[i] = b_v[colv];
  }
  const float bg2 = b_g2[0];

  // persistent accumulators (registers, no LDS atomics)
  float vacc0[4] = {0.f, 0.f, 0.f, 0.f};
  float vacc1[4] = {0.f, 0.f, 0.f, 0.f};
  float d0 = 0.f, d1 = 0.f;          // denominators (wave 0, lane==row)

  for (int node0 = node_lo; node0 < node_hi; node0 += 64) {
    // ---- stage A: 64 rows x 256 f32 -> bf16 LDS (zero-pad past node_hi) ---
    // Full unroll: all 16 dwordx4 loads in flight (one HBM round-trip, not 4).
    // NT loads: x is stream-once, block-exclusive -> keep Wt2 resident in L2.
#pragma unroll
    for (int rep = 0; rep < 16; ++rep) {
      int v   = rep * 256 + tid;     // float4 index; wave covers 1 KB rows
      int row = v >> 6;
      int c4  = v & 63;
      int node = node0 + row;
      f32x4 val = (f32x4){0.f, 0.f, 0.f, 0.f};
      if (node < node_hi)
        val = __builtin_nontemporal_load(
            (const f32x4*)(x + ((size_t)node << 8) + (c4 << 2)));
      ushort4 u;
      u.x = f32_bf16_rne(val[0]); u.y = f32_bf16_rne(val[1]);
      u.z = f32_bf16_rne(val[2]); u.w = f32_bf16_rne(val[3]);
      *(ushort4*)&As[row * 264 + (c4 << 2)] = u;
    }
    __syncthreads();   // S0: As ready

    // ---- phase 1: gate GEMM [64x256]@[256x128] (acc 32 regs) ----
    {
      f32x4 accg[4][2];
#pragma unroll
      for (int mt = 0; mt < 4; ++mt)
#pragma unroll
        for (int tn = 0; tn < 2; ++tn)
          accg[mt][tn] = (f32x4){0.f, 0.f, 0.f, 0.f};

#pragma unroll
      for (int c = 0; c < 8; ++c) {
        bf16x8 a[4];
#pragma unroll
        for (int mt = 0; mt < 4; ++mt)
          a[mt] = *(const bf16x8*)&As[(mt * 16 + l15) * 264 + c * 32 + quad * 8];
        int kc = c * 4 + quad;
#pragma unroll
        for (int tn = 0; tn < 2; ++tn) {
          int n = (w + 4 * tn) * 16 + l15;
          bf16x8 b = *(const bf16x8*)(Wt2 + (((kc * NCOLS) + n) << 3));
#pragma unroll
          for (int mt = 0; mt < 4; ++mt)
            accg[mt][tn] = __builtin_amdgcn_mfma_f32_16x16x32_bf16(
                a[mt], b, accg[mt][tn], 0, 0, 0);
        }
      }

      // silu(h) @ w_g2, butterfly over the 16 col-lanes of each quad
      float p[4][4];
#pragma unroll
      for (int mt = 0; mt < 4; ++mt)
#pragma unroll
        for (int r = 0; r < 4; ++r) {
          float s = 0.f;
#pragma unroll
          for (int tn = 0; tn < 2; ++tn) {
            float h = accg[mt][tn][r] + bg1r[tn];
            s += silu_f(h) * wg2r[tn];
          }
          p[mt][r] = s;
        }
#pragma unroll
      for (int off = 1; off < 16; off <<= 1)
#pragma unroll
        for (int mt = 0; mt < 4; ++mt)
#pragma unroll
          for (int r = 0; r < 4; ++r)
            p[mt][r] += __shfl_xor(p[mt][r], off, 64);
      if (l15 == 0)
#pragma unroll
        for (int mt = 0; mt < 4; ++mt)
#pragma unroll
          for (int r = 0; r < 4; ++r)
            gate_part[w][mt * 16 + quad * 4 + r] = p[mt][r];
    }
    __syncthreads();   // S1: gate partials ready

    // ---- e = exp(gate); no max-shift (gates are O(1)); denom in regs ----
    if (tid < 64) {
      int row = tid;
      int node = node0 + row;
      float e = 0.f;
      if (node < node_hi) {
        float g = gate_part[0][row] + gate_part[1][row] +
                  gate_part[2][row] + gate_part[3][row] + bg2;
        e = __expf(g);
        if (node < split) d0 += e; else d1 += e;
      }
      es[row] = e;
    }
    __syncthreads();   // S2: es ready

    // ---- phase 2: value GEMM in 2 chunks of [64x256]@[256x128] + fold ----
    VALUE_CHUNK(0)
    __builtin_amdgcn_sched_barrier(0);   // keep chunks sequential: acc reuse
    VALUE_CHUNK(1)

    __syncthreads();   // S3: done reading As/es before next staging
  }

  // ---- final reductions & store ----
#pragma unroll
  for (int tn = 0; tn < 4; ++tn) {
    vacc0[tn] += __shfl_xor(vacc0[tn], 16, 64);
    vacc0[tn] += __shfl_xor(vacc0[tn], 32, 64);
    vacc1[tn] += __shfl_xor(vacc1[tn], 16, 64);
    vacc1[tn] += __shfl_xor(vacc1[tn], 32, 64);
  }
  if (w == 0) {
#pragma unroll
    for (int off = 1; off < 64; off <<= 1) {
      d0 += __shfl_xor(d0, off, 64);
      d1 += __shfl_xor(d1, off, 64);
    }
    if (lane == 0) { denom_s[0] = d0; denom_s[1] = d1; }
  }
  __syncthreads();

  if (quad == 0) {
    float inv0 = 1.0f / (denom_s[0] + 1e-16f);
    float inv1 = 1.0f / (denom_s[1] + 1e-16f);
#pragma unroll
    for (int tn = 0; tn < 4; ++tn) {
      int colv = (w + 4 * (tn + 2)) * 16 + l15 - 128;
      out[(size_t)g0 * 256 + colv]       = vacc0[tn] * inv0;
      out[(size_t)(g0 + 1) * 256 + colv] = vacc1[tn] * inv1;
    }
  }
}

extern "C" void kernel_launch(void* const* d_in, const int* in_sizes, int n_in,
                              void* d_out, int out_size, void* d_ws, size_t ws_size,
                              hipStream_t stream) {
  const float* x    = (const float*)d_in[0];
  const int*   batch= (const int*)d_in[1];
  const float* w_g1 = (const float*)d_in[2];
  const float* b_g1 = (const float*)d_in[3];
  const float* w_g2 = (const float*)d_in[4];
  const float* b_g2 = (const float*)d_in[5];
  const float* w_v  = (const float*)d_in[6];
  const float* b_v  = (const float*)d_in[7];
  float* out = (float*)d_out;
  const int N = in_sizes[0] / HIDDEN;

  unsigned short* Wt2 = (unsigned short*)d_ws;                       // 192 KB
  int* seg = (int*)((char*)d_ws + (size_t)NCOLS * HIDDEN * sizeof(unsigned short));

  seg_starts_kernel<<<(N + 255) / 256, 256, 0, stream>>>(batch, seg, N);
  convert_w_kernel<<<(NCOLS * HIDDEN) / 256, 256, 0, stream>>>(w_g1, w_v, Wt2);
  attn_readout_kernel<<<NUM_GRAPHS / GPB, 256, 0, stream>>>(
      x, b_g1, w_g2, b_g2, b_v, Wt2, seg, out);
}

// Round 2
// 1171.447 us; speedup vs baseline: 1.3896x; 1.3896x over previous
//
#include <hip/hip_runtime.h>
#include <hip/hip_bf16.h>

#define HIDDEN 256
#define H2 128
#define NCOLS 384          // 128 gate-hidden cols + 256 value cols
#define NUM_GRAPHS 8192
#define GPB 2              // graphs per block (sorted batch => contiguous rows)

typedef short bf16x8 __attribute__((ext_vector_type(8)));
typedef float f32x4 __attribute__((ext_vector_type(4)));

__device__ __forceinline__ unsigned short f32_bf16_rne(float f) {
  union { float f; unsigned int u; } v; v.f = f;
  unsigned int u = v.u;
  unsigned int lsb = (u >> 16) & 1u;
  u += 0x7fffu + lsb;
  return (unsigned short)(u >> 16);
}

__device__ __forceinline__ float silu_f(float h) {
  return h / (1.0f + __expf(-h));
}

// seg[g] = first node index whose batch >= g ; seg[NUM_GRAPHS] = N
__global__ void seg_starts_kernel(const int* __restrict__ batch,
                                  int* __restrict__ seg, int N) {
  int i = blockIdx.x * blockDim.x + threadIdx.x;
  if (i >= N) return;
  int cur = batch[i];
  int prev = (i == 0) ? -1 : batch[i - 1];
  for (int g = prev + 1; g <= cur; ++g) seg[g] = i;
  if (i == N - 1)
    for (int g = cur + 1; g <= NUM_GRAPHS; ++g) seg[g] = N;
}

// Wt2[(k>>3)*NCOLS*8 + n*8 + (k&7)] = bf16(W[k][n]); W = [w_g1 | w_v]
// Layout makes a wave's MFMA B-fragment load fully coalesced from global/L2.
__global__ void convert_w_kernel(const float* __restrict__ w_g1,
                                 const float* __restrict__ w_v,
                                 unsigned short* __restrict__ Wt2) {
  int idx = blockIdx.x * blockDim.x + threadIdx.x;   // 0 .. 98303
  int j  = idx & 7;
  int n  = (idx >> 3) % NCOLS;
  int kc = idx / (NCOLS * 8);
  int k  = kc * 8 + j;
  float v = (n < H2) ? w_g1[k * H2 + n] : w_v[k * HIDDEN + (n - H2)];
  Wt2[idx] = f32_bf16_rne(v);
}

// __launch_bounds__(256, 3): 3 blocks/CU -> VGPR cap 170 (was 4 -> cap 128).
// At cap 128 the phase-2 demand (~64 acc + 16 a-frags + hoisted Wt2 b-frags
// + ~25 persistent) exceeded the budget and the allocator round-tripped ~1 GB
// of scratch per dispatch (WRITE_SIZE 965 MB vs 8 MB of real output; FETCH
// 1.26 GB vs 512 MB of x). Cap 170 gives the scheduler slack to hoist b-loads
// without spilling. LDS 35 KB * 3 = 105 KB <= 160 KB. Measured occupancy at
// cap-128 was only ~13 waves/CU anyway, so 12 waves/CU costs ~nothing.
__launch_bounds__(256, 3)
__global__ void attn_readout_kernel(
    const float* __restrict__ x,
    const float* __restrict__ b_g1,
    const float* __restrict__ w_g2,
    const float* __restrict__ b_g2,
    const float* __restrict__ b_v,
    const unsigned short* __restrict__ Wt2,
    const int* __restrict__ seg,
    float* __restrict__ out)
{
  // row stride 264 shorts (+8 pad)
  __shared__ unsigned short As[64 * 264];
  __shared__ float gate_part[4][64];
  __shared__ float es[64];
  __shared__ float denom_s[2];

  const int tid  = threadIdx.x;
  const int w    = tid >> 6;        // wave 0..3
  const int lane = tid & 63;
  const int l15  = lane & 15;
  const int quad = lane >> 4;

  const int g0      = blockIdx.x * GPB;
  const int node_lo = seg[g0];
  const int split   = seg[g0 + 1];   // first node of graph g0+1
  const int node_hi = seg[g0 + 2];

  // per-lane constants: wave w owns n-tiles {w, w+4, ..., w+20}
  float bg1r[2], wg2r[2], bvr[4];
#pragma unroll
  for (int i = 0; i < 2; ++i) {
    int col = (w + 4 * i) * 16 + l15;               // gate cols [0,128)
    bg1r[i] = b_g1[col];
    wg2r[i] = w_g2[col];
  }
#pragma unroll
  for (int i = 0; i < 4; ++i) {
    int colv = (w + 4 * (i + 2)) * 16 + l15 - 128;  // value cols [0,256)
    bvr[i] = b_v[colv];
  }
  const float bg2 = b_g2[0];

  // persistent accumulators (registers, no LDS atomics)
  float vacc0[4] = {0.f, 0.f, 0.f, 0.f};
  float vacc1[4] = {0.f, 0.f, 0.f, 0.f};
  float d0 = 0.f, d1 = 0.f;          // denominators (wave 0, lane==row)

  for (int node0 = node_lo; node0 < node_hi; node0 += 64) {
    // ---- stage A: 64 rows x 256 f32 -> bf16 LDS (zero-pad past node_hi) ---
    // unroll 4: only 4 float4 loads in flight (16 regs) -- full unroll held
    // 64 regs of destinations live and caused spill (round-1 regression).
    // NT loads: x is stream-once, block-exclusive -> don't pollute L2.
#pragma unroll 4
    for (int rep = 0; rep < 16; ++rep) {
      int v   = rep * 256 + tid;     // float4 index; wave covers 1 KB rows
      int row = v >> 6;
      int c4  = v & 63;
      int node = node0 + row;
      f32x4 val = (f32x4){0.f, 0.f, 0.f, 0.f};
      if (node < node_hi)
        val = __builtin_nontemporal_load(
            (const f32x4*)(x + ((size_t)node << 8) + (c4 << 2)));
      ushort4 u;
      u.x = f32_bf16_rne(val[0]); u.y = f32_bf16_rne(val[1]);
      u.z = f32_bf16_rne(val[2]); u.w = f32_bf16_rne(val[3]);
      *(ushort4*)&As[row * 264 + (c4 << 2)] = u;
    }
    __syncthreads();   // S0: As ready

    // ---- phase 1: gate GEMM [64x256]@[256x128] (acc 32 regs) ----
    {
      f32x4 accg[4][2];
#pragma unroll
      for (int mt = 0; mt < 4; ++mt)
#pragma unroll
        for (int tn = 0; tn < 2; ++tn)
          accg[mt][tn] = (f32x4){0.f, 0.f, 0.f, 0.f};

#pragma unroll
      for (int c = 0; c < 8; ++c) {
        bf16x8 a[4];
#pragma unroll
        for (int mt = 0; mt < 4; ++mt)
          a[mt] = *(const bf16x8*)&As[(mt * 16 + l15) * 264 + c * 32 + quad * 8];
        int kc = c * 4 + quad;
#pragma unroll
        for (int tn = 0; tn < 2; ++tn) {
          int n = (w + 4 * tn) * 16 + l15;
          bf16x8 b = *(const bf16x8*)(Wt2 + (((kc * NCOLS) + n) << 3));
#pragma unroll
          for (int mt = 0; mt < 4; ++mt)
            accg[mt][tn] = __builtin_amdgcn_mfma_f32_16x16x32_bf16(
                a[mt], b, accg[mt][tn], 0, 0, 0);
        }
      }

      // silu(h) @ w_g2, butterfly over the 16 col-lanes of each quad
      float p[4][4];
#pragma unroll
      for (int mt = 0; mt < 4; ++mt)
#pragma unroll
        for (int r = 0; r < 4; ++r) {
          float s = 0.f;
#pragma unroll
          for (int tn = 0; tn < 2; ++tn) {
            float h = accg[mt][tn][r] + bg1r[tn];
            s += silu_f(h) * wg2r[tn];
          }
          p[mt][r] = s;
        }
#pragma unroll
      for (int off = 1; off < 16; off <<= 1)
#pragma unroll
        for (int mt = 0; mt < 4; ++mt)
#pragma unroll
          for (int r = 0; r < 4; ++r)
            p[mt][r] += __shfl_xor(p[mt][r], off, 64);
      if (l15 == 0)
#pragma unroll
        for (int mt = 0; mt < 4; ++mt)
#pragma unroll
          for (int r = 0; r < 4; ++r)
            gate_part[w][mt * 16 + quad * 4 + r] = p[mt][r];
    }
    __syncthreads();   // S1: gate partials ready

    // ---- e = exp(gate); no max-shift (gates are O(1)); denom in regs ----
    if (tid < 64) {
      int row = tid;
      int node = node0 + row;
      float e = 0.f;
      if (node < node_hi) {
        float g = gate_part[0][row] + gate_part[1][row] +
                  gate_part[2][row] + gate_part[3][row] + bg2;
        e = __expf(g);
        if (node < split) d0 += e; else d1 += e;
      }
      es[row] = e;
    }
    __syncthreads();   // S2: es ready

    // ---- phase 2: value GEMM [64x256]@[256x256] (acc 64 regs) + fold ----
    {
      f32x4 accv[4][4];
#pragma unroll
      for (int mt = 0; mt < 4; ++mt)
#pragma unroll
        for (int tn = 0; tn < 4; ++tn)
          accv[mt][tn] = (f32x4){0.f, 0.f, 0.f, 0.f};

#pragma unroll
      for (int c = 0; c < 8; ++c) {
        bf16x8 a[4];
#pragma unroll
        for (int mt = 0; mt < 4; ++mt)
          a[mt] = *(const bf16x8*)&As[(mt * 16 + l15) * 264 + c * 32 + quad * 8];
        int kc = c * 4 + quad;
#pragma unroll
        for (int tn = 0; tn < 4; ++tn) {
          int n = (w + 4 * (tn + 2)) * 16 + l15;
          bf16x8 b = *(const bf16x8*)(Wt2 + (((kc * NCOLS) + n) << 3));
#pragma unroll
          for (int mt = 0; mt < 4; ++mt)
            accv[mt][tn] = __builtin_amdgcn_mfma_f32_16x16x32_bf16(
                a[mt], b, accv[mt][tn], 0, 0, 0);
        }
      }

      // fold: vacc[gi][tn] += e * silu(v); gi from sorted-row split, branchless
#pragma unroll
      for (int mt = 0; mt < 4; ++mt)
#pragma unroll
        for (int r = 0; r < 4; ++r) {
          int row  = mt * 16 + quad * 4 + r;
          int node = node0 + row;
          float e  = es[row];                  // 0 for padded rows
          float se0 = (node < split) ? e : 0.f;
          float se1 = e - se0;
#pragma unroll
          for (int tn = 0; tn < 4; ++tn) {
            float s = silu_f(accv[mt][tn][r] + bvr[tn]);
            vacc0[tn] += se0 * s;
            vacc1[tn] += se1 * s;
          }
        }
    }
    __syncthreads();   // S3: done reading As/es before next staging
  }

  // ---- final reductions & store ----
#pragma unroll
  for (int tn = 0; tn < 4; ++tn) {
    vacc0[tn] += __shfl_xor(vacc0[tn], 16, 64);
    vacc0[tn] += __shfl_xor(vacc0[tn], 32, 64);
    vacc1[tn] += __shfl_xor(vacc1[tn], 16, 64);
    vacc1[tn] += __shfl_xor(vacc1[tn], 32, 64);
  }
  if (w == 0) {
#pragma unroll
    for (int off = 1; off < 64; off <<= 1) {
      d0 += __shfl_xor(d0, off, 64);
      d1 += __shfl_xor(d1, off, 64);
    }
    if (lane == 0) { denom_s[0] = d0; denom_s[1] = d1; }
  }
  __syncthreads();

  if (quad == 0) {
    float inv0 = 1.0f / (denom_s[0] + 1e-16f);
    float inv1 = 1.0f / (denom_s[1] + 1e-16f);
#pragma unroll
    for (int tn = 0; tn < 4; ++tn) {
      int colv = (w + 4 * (tn + 2)) * 16 + l15 - 128;
      out[(size_t)g0 * 256 + colv]       = vacc0[tn] * inv0;
      out[(size_t)(g0 + 1) * 256 + colv] = vacc1[tn] * inv1;
    }
  }
}

extern "C" void kernel_launch(void* const* d_in, const int* in_sizes, int n_in,
                              void* d_out, int out_size, void* d_ws, size_t ws_size,
                              hipStream_t stream) {
  const float* x    = (const float*)d_in[0];
  const int*   batch= (const int*)d_in[1];
  const float* w_g1 = (const float*)d_in[2];
  const float* b_g1 = (const float*)d_in[3];
  const float* w_g2 = (const float*)d_in[4];
  const float* b_g2 = (const float*)d_in[5];
  const float* w_v  = (const float*)d_in[6];
  const float* b_v  = (const float*)d_in[7];
  float* out = (float*)d_out;
  const int N = in_sizes[0] / HIDDEN;

  unsigned short* Wt2 = (unsigned short*)d_ws;                       // 192 KB
  int* seg = (int*)((char*)d_ws + (size_t)NCOLS * HIDDEN * sizeof(unsigned short));

  seg_starts_kernel<<<(N + 255) / 256, 256, 0, stream>>>(batch, seg, N);
  convert_w_kernel<<<(NCOLS * HIDDEN) / 256, 256, 0, stream>>>(w_g1, w_v, Wt2);
  attn_readout_kernel<<<NUM_GRAPHS / GPB, 256, 0, stream>>>(
      x, b_g1, w_g2, b_g2, b_v, Wt2, seg, out);
}

// Round 3
// 907.313 us; speedup vs baseline: 1.7941x; 1.2911x over previous
//
#include <hip/hip_runtime.h>
#include <hip/hip_bf16.h>

#define HIDDEN 256
#define H2 128
#define NCOLS 384          // 128 gate-hidden cols + 256 value cols
#define NUM_GRAPHS 8192
#define GPB 2              // graphs per block-pair (sorted batch => contiguous rows)
#define PPB 8              // graph-pairs per persistent block
#define NBLK (NUM_GRAPHS / GPB / PPB)   // 512 blocks

typedef short bf16x8 __attribute__((ext_vector_type(8)));
typedef float f32x4 __attribute__((ext_vector_type(4)));

__device__ __forceinline__ unsigned short f32_bf16_rne(float f) {
  union { float f; unsigned int u; } v; v.f = f;
  unsigned int u = v.u;
  unsigned int lsb = (u >> 16) & 1u;
  u += 0x7fffu + lsb;
  return (unsigned short)(u >> 16);
}

__device__ __forceinline__ float silu_f(float h) {
  return h / (1.0f + __expf(-h));
}

// seg[g] = first node index whose batch >= g ; seg[NUM_GRAPHS] = N
__global__ void seg_starts_kernel(const int* __restrict__ batch,
                                  int* __restrict__ seg, int N) {
  int i = blockIdx.x * blockDim.x + threadIdx.x;
  if (i >= N) return;
  int cur = batch[i];
  int prev = (i == 0) ? -1 : batch[i - 1];
  for (int g = prev + 1; g <= cur; ++g) seg[g] = i;
  if (i == N - 1)
    for (int g = cur + 1; g <= NUM_GRAPHS; ++g) seg[g] = N;
}

// Wt2[(k>>3)*NCOLS*8 + n*8 + (k&7)] = bf16(W[k][n]); W = [w_g1 | w_v]
__global__ void convert_w_kernel(const float* __restrict__ w_g1,
                                 const float* __restrict__ w_v,
                                 unsigned short* __restrict__ Wt2) {
  int idx = blockIdx.x * blockDim.x + threadIdx.x;   // 0 .. 98303
  int j  = idx & 7;
  int n  = (idx >> 3) % NCOLS;
  int kc = idx / (NCOLS * 8);
  int k  = kc * 8 + j;
  float v = (n < H2) ? w_g1[k * H2 + n] : w_v[k * HIDDEN + (n - H2)];
  Wt2[idx] = f32_bf16_rne(v);
}

// 8-wave persistent blocks, weights register-resident.
// Wave w owns gate tile w (cols w*16..w*16+15) and value tiles 8+w, 16+w
// (value cols w*16.. and 128+w*16..). Per lane: 3 tiles x 8 kc x 16 B = 96
// VGPRs of loop-invariant B-fragments -> the K-loop has ZERO global loads,
// killing the scratch spill that cost ~1.5 GB of HBM round-trips (the
// scheduler's appetite to hoist b-frag loads exceeded any reachable cap).
// __launch_bounds__(512,2): 1 block/CU, VGPR cap 256; static demand ~200.
// Latency hidden by As double-buffer + async-stage split: next tile's NT
// loads issue before the GEMMs, convert+ds_write after (T14).
__launch_bounds__(512, 2)
__global__ void attn_readout_kernel(
    const float* __restrict__ x,
    const float* __restrict__ b_g1,
    const float* __restrict__ w_g2,
    const float* __restrict__ b_g2,
    const float* __restrict__ b_v,
    const unsigned short* __restrict__ Wt2,
    const int* __restrict__ seg,
    float* __restrict__ out)
{
  // row stride 264 shorts (+8 pad); double-buffered: 2 x 33 KB = 67.6 KB
  __shared__ unsigned short As[2][64 * 264];
  __shared__ float gate_part[8][64];
  __shared__ float es[64];
  __shared__ float denom_s[2];

  const int tid  = threadIdx.x;
  const int w    = tid >> 6;        // wave 0..7
  const int lane = tid & 63;
  const int l15  = lane & 15;
  const int quad = lane >> 4;

  // ---- one-shot: loop-invariant B-fragments into registers (96 VGPRs) ----
  bf16x8 Bg[8], Bv0[8], Bv1[8];
#pragma unroll
  for (int c = 0; c < 8; ++c) {
    int kc = c * 4 + quad;
    const unsigned short* kb = Wt2 + (((size_t)kc * NCOLS) << 3);
    Bg[c]  = *(const bf16x8*)(kb + ((w * 16 + l15) << 3));
    Bv0[c] = *(const bf16x8*)(kb + ((128 + w * 16 + l15) << 3));
    Bv1[c] = *(const bf16x8*)(kb + ((256 + w * 16 + l15) << 3));
  }
  const float bg1 = b_g1[w * 16 + l15];
  const float wg2 = w_g2[w * 16 + l15];
  const float bv0 = b_v[w * 16 + l15];
  const float bv1 = b_v[128 + w * 16 + l15];
  const float bg2 = b_g2[0];

  for (int pp = 0; pp < PPB; ++pp) {
    const int g0      = (blockIdx.x * PPB + pp) * GPB;
    const int node_lo = seg[g0];
    const int split   = seg[g0 + 1];   // first node of graph g0+1
    const int node_hi = seg[g0 + 2];

    float vg0t0 = 0.f, vg0t1 = .0f, vg1t0 = 0.f, vg1t1 = 0.f;
    float d0 = 0.f, d1 = 0.f;          // denominators (wave 0, lane==row)

    // ---- prologue: stage first tile serially ----
    if (node_lo < node_hi) {
#pragma unroll
      for (int i = 0; i < 8; ++i) {
        int v = i * 512 + tid, row = v >> 6, c4 = v & 63;
        int node = node_lo + row;
        f32x4 val = (f32x4){0.f, 0.f, 0.f, 0.f};
        if (node < node_hi)
          val = __builtin_nontemporal_load(
              (const f32x4*)(x + ((size_t)node << 8) + (c4 << 2)));
        ushort4 u;
        u.x = f32_bf16_rne(val[0]); u.y = f32_bf16_rne(val[1]);
        u.z = f32_bf16_rne(val[2]); u.w = f32_bf16_rne(val[3]);
        *(ushort4*)&As[0][row * 264 + (c4 << 2)] = u;
      }
    }
    __syncthreads();   // S0: tile 0 staged

    int cur = 0;
    for (int node0 = node_lo; node0 < node_hi; node0 += 64, cur ^= 1) {
      const int  next0     = node0 + 64;
      const bool have_next = (next0 < node_hi);

      // issue next tile's loads EARLY (drained only after value GEMM)
      f32x4 sv[8];
      if (have_next) {
#pragma unroll
        for (int i = 0; i < 8; ++i) {
          int v = i * 512 + tid, row = v >> 6, c4 = v & 63;
          int node = next0 + row;
          sv[i] = (f32x4){0.f, 0.f, 0.f, 0.f};
          if (node < node_hi)
            sv[i] = __builtin_nontemporal_load(
                (const f32x4*)(x + ((size_t)node << 8) + (c4 << 2)));
        }
      }
      __builtin_amdgcn_sched_barrier(0);   // pin load issue above compute

      // ---- phase 1: gate GEMM [64x256]@[256x16] per wave ----
      {
        f32x4 accg[4];
#pragma unroll
        for (int mt = 0; mt < 4; ++mt) accg[mt] = (f32x4){0.f, 0.f, 0.f, 0.f};
#pragma unroll
        for (int c = 0; c < 8; ++c) {
          bf16x8 a[4];
#pragma unroll
          for (int mt = 0; mt < 4; ++mt)
            a[mt] = *(const bf16x8*)&As[cur][(mt * 16 + l15) * 264 + c * 32 + quad * 8];
#pragma unroll
          for (int mt = 0; mt < 4; ++mt)
            accg[mt] = __builtin_amdgcn_mfma_f32_16x16x32_bf16(
                a[mt], Bg[c], accg[mt], 0, 0, 0);
        }
        // silu(h) * w_g2, butterfly over the 16 col-lanes of each quad
        float p[4][4];
#pragma unroll
        for (int mt = 0; mt < 4; ++mt)
#pragma unroll
          for (int r = 0; r < 4; ++r)
            p[mt][r] = silu_f(accg[mt][r] + bg1) * wg2;
#pragma unroll
        for (int off = 1; off < 16; off <<= 1)
#pragma unroll
          for (int mt = 0; mt < 4; ++mt)
#pragma unroll
            for (int r = 0; r < 4; ++r)
              p[mt][r] += __shfl_xor(p[mt][r], off, 64);
        if (l15 == 0)
#pragma unroll
          for (int mt = 0; mt < 4; ++mt)
#pragma unroll
            for (int r = 0; r < 4; ++r)
              gate_part[w][mt * 16 + quad * 4 + r] = p[mt][r];
      }
      __syncthreads();   // S1: gate partials ready

      // ---- e = exp(gate); denom in wave-0 regs ----
      if (tid < 64) {
        int row = tid, node = node0 + row;
        float e = 0.f;
        if (node < node_hi) {
          float g = bg2;
#pragma unroll
          for (int ww = 0; ww < 8; ++ww) g += gate_part[ww][row];
          e = __expf(g);
          if (node < split) d0 += e; else d1 += e;
        }
        es[row] = e;
      }
      __syncthreads();   // S2: es ready

      // ---- phase 2: value GEMM [64x256]@[256x32] per wave + fold ----
      {
        f32x4 accv[4][2];
#pragma unroll
        for (int mt = 0; mt < 4; ++mt) {
          accv[mt][0] = (f32x4){0.f, 0.f, 0.f, 0.f};
          accv[mt][1] = (f32x4){0.f, 0.f, 0.f, 0.f};
        }
#pragma unroll
        for (int c = 0; c < 8; ++c) {
          bf16x8 a[4];
#pragma unroll
          for (int mt = 0; mt < 4; ++mt)
            a[mt] = *(const bf16x8*)&As[cur][(mt * 16 + l15) * 264 + c * 32 + quad * 8];
#pragma unroll
          for (int mt = 0; mt < 4; ++mt) {
            accv[mt][0] = __builtin_amdgcn_mfma_f32_16x16x32_bf16(
                a[mt], Bv0[c], accv[mt][0], 0, 0, 0);
            accv[mt][1] = __builtin_amdgcn_mfma_f32_16x16x32_bf16(
                a[mt], Bv1[c], accv[mt][1], 0, 0, 0);
          }
        }
#pragma unroll
        for (int mt = 0; mt < 4; ++mt)
#pragma unroll
          for (int r = 0; r < 4; ++r) {
            int row  = mt * 16 + quad * 4 + r;
            int node = node0 + row;
            float e  = es[row];                  // 0 for padded rows
            float se0 = (node < split) ? e : 0.f;
            float se1 = e - se0;
            float s0 = silu_f(accv[mt][0][r] + bv0);
            float s1 = silu_f(accv[mt][1][r] + bv1);
            vg0t0 += se0 * s0; vg0t1 += se0 * s1;
            vg1t0 += se1 * s0; vg1t1 += se1 * s1;
          }
      }

      // drain next tile's loads, convert, write other buffer (T14 late-write)
      if (have_next) {
#pragma unroll
        for (int i = 0; i < 8; ++i) {
          int v = i * 512 + tid, row = v >> 6, c4 = v & 63;
          ushort4 u;
          u.x = f32_bf16_rne(sv[i][0]); u.y = f32_bf16_rne(sv[i][1]);
          u.z = f32_bf16_rne(sv[i][2]); u.w = f32_bf16_rne(sv[i][3]);
          *(ushort4*)&As[cur ^ 1][row * 264 + (c4 << 2)] = u;
        }
      }
      __syncthreads();   // S3: next buffer staged; everyone done with cur
    }

    // ---- per-pair epilogue: reduce & store ----
    vg0t0 += __shfl_xor(vg0t0, 16, 64); vg0t0 += __shfl_xor(vg0t0, 32, 64);
    vg0t1 += __shfl_xor(vg0t1, 16, 64); vg0t1 += __shfl_xor(vg0t1, 32, 64);
    vg1t0 += __shfl_xor(vg1t0, 16, 64); vg1t0 += __shfl_xor(vg1t0, 32, 64);
    vg1t1 += __shfl_xor(vg1t1, 16, 64); vg1t1 += __shfl_xor(vg1t1, 32, 64);
    if (w == 0) {
#pragma unroll
      for (int off = 1; off < 64; off <<= 1) {
        d0 += __shfl_xor(d0, off, 64);
        d1 += __shfl_xor(d1, off, 64);
      }
      if (lane == 0) { denom_s[0] = d0; denom_s[1] = d1; }
    }
    __syncthreads();

    if (quad == 0) {
      float inv0 = 1.0f / (denom_s[0] + 1e-16f);
      float inv1 = 1.0f / (denom_s[1] + 1e-16f);
      out[(size_t)g0 * 256 + w * 16 + l15]             = vg0t0 * inv0;
      out[(size_t)g0 * 256 + 128 + w * 16 + l15]       = vg0t1 * inv0;
      out[(size_t)(g0 + 1) * 256 + w * 16 + l15]       = vg1t0 * inv1;
      out[(size_t)(g0 + 1) * 256 + 128 + w * 16 + l15] = vg1t1 * inv1;
    }
    __syncthreads();   // protect denom_s from next pair's overwrite
  }
}

extern "C" void kernel_launch(void* const* d_in, const int* in_sizes, int n_in,
                              void* d_out, int out_size, void* d_ws, size_t ws_size,
                              hipStream_t stream) {
  const float* x    = (const float*)d_in[0];
  const int*   batch= (const int*)d_in[1];
  const float* w_g1 = (const float*)d_in[2];
  const float* b_g1 = (const float*)d_in[3];
  const float* w_g2 = (const float*)d_in[4];
  const float* b_g2 = (const float*)d_in[5];
  const float* w_v  = (const float*)d_in[6];
  const float* b_v  = (const float*)d_in[7];
  float* out = (float*)d_out;
  const int N = in_sizes[0] / HIDDEN;

  unsigned short* Wt2 = (unsigned short*)d_ws;                       // 192 KB
  int* seg = (int*)((char*)d_ws + (size_t)NCOLS * HIDDEN * sizeof(unsigned short));

  seg_starts_kernel<<<(N + 255) / 256, 256, 0, stream>>>(batch, seg, N);
  convert_w_kernel<<<(NCOLS * HIDDEN) / 256, 256, 0, stream>>>(w_g1, w_v, Wt2);
  attn_readout_kernel<<<NBLK, 512, 0, stream>>>(
      x, b_g1, w_g2, b_g2, b_v, Wt2, seg, out);
}

// Round 4
// 865.814 us; speedup vs baseline: 1.8801x; 1.0479x over previous
//
#include <hip/hip_runtime.h>
#include <hip/hip_bf16.h>

#define HIDDEN 256
#define H2 128
#define NCOLS 384          // 128 gate-hidden cols + 256 value cols
#define NUM_GRAPHS 8192
#define GPB 2              // graphs per pair (sorted batch => contiguous rows)
#define PPB 4              // graph-pairs per block
#define NBLK (NUM_GRAPHS / GPB / PPB)   // 1024 blocks

typedef short bf16x8 __attribute__((ext_vector_type(8)));
typedef float f32x4 __attribute__((ext_vector_type(4)));

__device__ __forceinline__ float silu_f(float h) {
  return h / (1.0f + __expf(-h));
}

// packed f32x2 -> bf16x2 (RNE), low = a
__device__ __forceinline__ unsigned int cvt_pk_bf16(float a, float b) {
  unsigned int r;
  asm volatile("v_cvt_pk_bf16_f32 %0, %1, %2" : "=v"(r) : "v"(a), "v"(b));
  return r;
}

// sum across each 16-lane row via DPP row_shr; total lands in lane 15 of row.
// Replaces the 4-step __shfl_xor butterfly (ds_bpermute) that accounted for
// ~all SQ_LDS_BANK_CONFLICT (19M cycles) and a ~200-cyc DS latency chain.
__device__ __forceinline__ float dpp_sum16(float v) {
  int t;
  t = __builtin_amdgcn_update_dpp(0, __builtin_bit_cast(int, v), 0x111, 0xf, 0xf, true);
  v += __builtin_bit_cast(float, t);
  t = __builtin_amdgcn_update_dpp(0, __builtin_bit_cast(int, v), 0x112, 0xf, 0xf, true);
  v += __builtin_bit_cast(float, t);
  t = __builtin_amdgcn_update_dpp(0, __builtin_bit_cast(int, v), 0x114, 0xf, 0xf, true);
  v += __builtin_bit_cast(float, t);
  t = __builtin_amdgcn_update_dpp(0, __builtin_bit_cast(int, v), 0x118, 0xf, 0xf, true);
  v += __builtin_bit_cast(float, t);
  return v;
}

// seg[g] = first node index whose batch >= g ; seg[NUM_GRAPHS] = N
__global__ void seg_starts_kernel(const int* __restrict__ batch,
                                  int* __restrict__ seg, int N) {
  int i = blockIdx.x * blockDim.x + threadIdx.x;
  if (i >= N) return;
  int cur = batch[i];
  int prev = (i == 0) ? -1 : batch[i - 1];
  for (int g = prev + 1; g <= cur; ++g) seg[g] = i;
  if (i == N - 1)
    for (int g = cur + 1; g <= NUM_GRAPHS; ++g) seg[g] = N;
}

// Wt2[(k>>3)*NCOLS*8 + n*8 + (k&7)] = bf16(W[k][n]); W = [w_g1 | w_v]
__global__ void convert_w_kernel(const float* __restrict__ w_g1,
                                 const float* __restrict__ w_v,
                                 unsigned short* __restrict__ Wt2) {
  int idx = blockIdx.x * blockDim.x + threadIdx.x;   // 0 .. 98303
  int j  = idx & 7;
  int n  = (idx >> 3) % NCOLS;
  int kc = idx / (NCOLS * 8);
  int k  = kc * 8 + j;
  float v = (n < H2) ? w_g1[k * H2 + n] : w_v[k * HIDDEN + (n - H2)];
  union { float f; unsigned int u; } c; c.f = v;
  unsigned int u = c.u; u += 0x7fffu + ((u >> 16) & 1u);
  Wt2[idx] = (unsigned short)(u >> 16);
}

// 8-wave blocks, weights register-resident (96 VGPR/lane), 1 block/CU.
// Single __syncthreads per tile: gate+value GEMMs merged into one MFMA burst
// (A-frags read once), stage-drain lands BEFORE the barrier, and As/gate_part/
// es are all double-buffered so every cross-tile hazard is split by one S1.
// exp/denominator computed redundantly by all waves (lane = row) -> no
// single-wave phase, no denominator broadcast, barrier-free pair epilogue.
// Cross-pair prefetch: last tile of pair p stages pair p+1's first tile
// (node ranges contiguous) -> one serial prologue per BLOCK.
__launch_bounds__(512, 2)
__global__ void attn_readout_kernel(
    const float* __restrict__ x,
    const float* __restrict__ b_g1,
    const float* __restrict__ w_g2,
    const float* __restrict__ b_g2,
    const float* __restrict__ b_v,
    const unsigned short* __restrict__ Wt2,
    const int* __restrict__ seg,
    float* __restrict__ out)
{
  // row stride 264 shorts (+8 pad); double-buffered
  __shared__ unsigned short As[2][64 * 264];   // 66 KB
  __shared__ float gate_part[2][8][64];        // 4 KB
  __shared__ float es2[2][64];                 // 0.5 KB

  const int tid  = threadIdx.x;
  const int w    = tid >> 6;        // wave 0..7
  const int lane = tid & 63;
  const int l15  = lane & 15;
  const int quad = lane >> 4;

  // ---- one-shot: loop-invariant B-fragments into registers (96 VGPRs) ----
  bf16x8 Bg[8], Bv0[8], Bv1[8];
#pragma unroll
  for (int c = 0; c < 8; ++c) {
    int kc = c * 4 + quad;
    const unsigned short* kb = Wt2 + (((size_t)kc * NCOLS) << 3);
    Bg[c]  = *(const bf16x8*)(kb + ((w * 16 + l15) << 3));
    Bv0[c] = *(const bf16x8*)(kb + ((128 + w * 16 + l15) << 3));
    Bv1[c] = *(const bf16x8*)(kb + ((256 + w * 16 + l15) << 3));
  }
  const float bg1 = b_g1[w * 16 + l15];
  const float wg2 = w_g2[w * 16 + l15];
  const float bv0 = b_v[w * 16 + l15];
  const float bv1 = b_v[128 + w * 16 + l15];
  const float bg2 = b_g2[0];

  const int gbase = blockIdx.x * (PPB * GPB);
  int  cur    = 0;
  bool staged = false;

  for (int pp = 0; pp < PPB; ++pp) {
    const int g0      = gbase + pp * GPB;
    const int node_lo = seg[g0];
    const int split   = seg[g0 + 1];
    const int node_hi = seg[g0 + 2];
    const int hi2     = (pp + 1 < PPB) ? seg[g0 + 4] : node_hi;

    float vg0t0 = 0.f, vg0t1 = 0.f, vg1t0 = 0.f, vg1t1 = 0.f;
    float d0 = 0.f, d1 = 0.f;      // per-lane (row=lane) partials, per wave

    if (node_lo < node_hi) {
      if (!staged) {
        // serial prologue: stage first tile of this pair
#pragma unroll
        for (int i = 0; i < 8; ++i) {
          int v = i * 512 + tid, row = v >> 6, c4 = v & 63;
          int node = node_lo + row;
          f32x4 val = (f32x4){0.f, 0.f, 0.f, 0.f};
          if (node < node_hi)
            val = __builtin_nontemporal_load(
                (const f32x4*)(x + ((size_t)node << 8) + (c4 << 2)));
          unsigned int lo = cvt_pk_bf16(val[0], val[1]);
          unsigned int hi = cvt_pk_bf16(val[2], val[3]);
          *(uint2*)&As[cur][row * 264 + (c4 << 2)] = make_uint2(lo, hi);
        }
        __syncthreads();
      }

      for (int node0 = node_lo; node0 < node_hi; node0 += 64) {
        const bool in_pair   = (node0 + 64 < node_hi);
        const int  nstart    = in_pair ? node0 + 64 : node_hi;   // next pair lo
        const int  nlimit    = in_pair ? node_hi    : hi2;
        const bool have_next = nstart < nlimit;

        // 1. issue next tile's loads early (drained before S1)
        f32x4 sv[8];
        if (have_next) {
#pragma unroll
          for (int i = 0; i < 8; ++i) {
            int v = i * 512 + tid, row = v >> 6, c4 = v & 63;
            int node = nstart + row;
            sv[i] = (f32x4){0.f, 0.f, 0.f, 0.f};
            if (node < nlimit)
              sv[i] = __builtin_nontemporal_load(
                  (const f32x4*)(x + ((size_t)node << 8) + (c4 << 2)));
          }
        }
        __builtin_amdgcn_sched_barrier(0);   // pin load issue above compute

        // 2. merged GEMM burst: A-frags read once, 12 MFMA per 4 ds_read
        f32x4 accg[4];
        f32x4 accv[4][2];
#pragma unroll
        for (int mt = 0; mt < 4; ++mt) {
          accg[mt]    = (f32x4){0.f, 0.f, 0.f, 0.f};
          accv[mt][0] = (f32x4){0.f, 0.f, 0.f, 0.f};
          accv[mt][1] = (f32x4){0.f, 0.f, 0.f, 0.f};
        }
        __builtin_amdgcn_s_setprio(1);
#pragma unroll
        for (int c = 0; c < 8; ++c) {
          bf16x8 a[4];
#pragma unroll
          for (int mt = 0; mt < 4; ++mt)
            a[mt] = *(const bf16x8*)&As[cur][(mt * 16 + l15) * 264 + c * 32 + quad * 8];
#pragma unroll
          for (int mt = 0; mt < 4; ++mt) {
            accg[mt]    = __builtin_amdgcn_mfma_f32_16x16x32_bf16(
                a[mt], Bg[c],  accg[mt],    0, 0, 0);
            accv[mt][0] = __builtin_amdgcn_mfma_f32_16x16x32_bf16(
                a[mt], Bv0[c], accv[mt][0], 0, 0, 0);
            accv[mt][1] = __builtin_amdgcn_mfma_f32_16x16x32_bf16(
                a[mt], Bv1[c], accv[mt][1], 0, 0, 0);
          }
        }
        __builtin_amdgcn_s_setprio(0);

        // 3. gate epilogue: silu * wg2, DPP row-reduce, lane15 writes
#pragma unroll
        for (int mt = 0; mt < 4; ++mt)
#pragma unroll
          for (int r = 0; r < 4; ++r) {
            float p = silu_f(accg[mt][r] + bg1) * wg2;
            p = dpp_sum16(p);
            if (l15 == 15)
              gate_part[cur][w][mt * 16 + quad * 4 + r] = p;
          }

        // 4. drain staged loads -> other As buffer (before the barrier)
        if (have_next) {
#pragma unroll
          for (int i = 0; i < 8; ++i) {
            int v = i * 512 + tid, row = v >> 6, c4 = v & 63;
            unsigned int lo = cvt_pk_bf16(sv[i][0], sv[i][1]);
            unsigned int hi = cvt_pk_bf16(sv[i][2], sv[i][3]);
            *(uint2*)&As[cur ^ 1][row * 264 + (c4 << 2)] = make_uint2(lo, hi);
          }
        }

        __syncthreads();   // S1: the ONLY barrier per tile

        // 5. e = exp(gate), all waves redundantly (lane = row)
        {
          int node = node0 + lane;
          float g = bg2;
#pragma unroll
          for (int ww = 0; ww < 8; ++ww) g += gate_part[cur][ww][lane];
          float e = (node < node_hi) ? __expf(g) : 0.f;
          es2[cur][lane] = e;              // identical value from every wave
          float se0 = (node < split) ? e : 0.f;
          d0 += se0;
          d1 += e - se0;
        }

        // 6. fold: vacc += e * silu(value)
#pragma unroll
        for (int mt = 0; mt < 4; ++mt)
#pragma unroll
          for (int r = 0; r < 4; ++r) {
            int row  = mt * 16 + quad * 4 + r;
            int node = node0 + row;
            float e  = es2[cur][row];          // broadcast read
            float se0 = (node < split) ? e : 0.f;
            float se1 = e - se0;
            float s0 = silu_f(accv[mt][0][r] + bv0);
            float s1 = silu_f(accv[mt][1][r] + bv1);
            vg0t0 += se0 * s0; vg0t1 += se0 * s1;
            vg1t0 += se1 * s0; vg1t1 += se1 * s1;
          }

        staged = have_next && !in_pair;   // prefetched next pair's first tile?
        cur ^= 1;
      }
    }

    // ---- pair epilogue: per-wave reduce & store (no barrier) ----
    vg0t0 += __shfl_xor(vg0t0, 16, 64); vg0t0 += __shfl_xor(vg0t0, 32, 64);
    vg0t1 += __shfl_xor(vg0t1, 16, 64); vg0t1 += __shfl_xor(vg0t1, 32, 64);
    vg1t0 += __shfl_xor(vg1t0, 16, 64); vg1t0 += __shfl_xor(vg1t0, 32, 64);
    vg1t1 += __shfl_xor(vg1t1, 16, 64); vg1t1 += __shfl_xor(vg1t1, 32, 64);
#pragma unroll
    for (int off = 1; off < 64; off <<= 1) {
      d0 += __shfl_xor(d0, off, 64);
      d1 += __shfl_xor(d1, off, 64);
    }
    if (quad == 0) {
      float inv0 = 1.0f / (d0 + 1e-16f);
      float inv1 = 1.0f / (d1 + 1e-16f);
      out[(size_t)g0 * 256 + w * 16 + l15]             = vg0t0 * inv0;
      out[(size_t)g0 * 256 + 128 + w * 16 + l15]       = vg0t1 * inv0;
      out[(size_t)(g0 + 1) * 256 + w * 16 + l15]       = vg1t0 * inv1;
      out[(size_t)(g0 + 1) * 256 + 128 + w * 16 + l15] = vg1t1 * inv1;
    }
  }
}

extern "C" void kernel_launch(void* const* d_in, const int* in_sizes, int n_in,
                              void* d_out, int out_size, void* d_ws, size_t ws_size,
                              hipStream_t stream) {
  const float* x    = (const float*)d_in[0];
  const int*   batch= (const int*)d_in[1];
  const float* w_g1 = (const float*)d_in[2];
  const float* b_g1 = (const float*)d_in[3];
  const float* w_g2 = (const float*)d_in[4];
  const float* b_g2 = (const float*)d_in[5];
  const float* w_v  = (const float*)d_in[6];
  const float* b_v  = (const float*)d_in[7];
  float* out = (float*)d_out;
  const int N = in_sizes[0] / HIDDEN;

  unsigned short* Wt2 = (unsigned short*)d_ws;                       // 192 KB
  int* seg = (int*)((char*)d_ws + (size_t)NCOLS * HIDDEN * sizeof(unsigned short));

  seg_starts_kernel<<<(N + 255) / 256, 256, 0, stream>>>(batch, seg, N);
  convert_w_kernel<<<(NCOLS * HIDDEN) / 256, 256, 0, stream>>>(w_g1, w_v, Wt2);
  attn_readout_kernel<<<NBLK, 512, 0, stream>>>(
      x, b_g1, w_g2, b_g2, b_v, Wt2, seg, out);
}